// Round 8
// baseline (5398.932 us; speedup 1.0000x reference)
//
#include <hip/hip_runtime.h>
#include <hip/hip_bf16.h>

// ---------------------------------------------------------------------------
// LSTM_66675072303478: 2-layer LSTM (B=512,S=128,E=7,H=1024) + FC(1024->672)
//
// v8: column-specialized XCDs -> weights L2-resident.
//  - XCD x owns gate rows [512x,512x+512) of BOTH layers (3 MB weights in its
//    4 MB L2; fetched ~once total, vs 12.7 GB re-streamed in v7).
//  - h exchange is cross-XCD: stores = relaxed agent atomic dwords (EA-point,
//    proven coherent class in v5), loads = plain cached (L2-shared) made safe
//    by 3-deep buffer rotation (no address re-written while a stale copy can
//    plausibly survive) + L1-only buffer_inv after each flag wait.
//  - Flags per m-tile (8 x cA, 8 x cB), relaxed atomics, cross-XCD.
//    L0(t): cA[mt]>=32t && cB[mt]>=32(t-2);  L1(t): cA[mt]>=32(t+1) && cB[mt]>=32t.
//  - h_a(t) -> bufA[(t+1)%3], h_b(t) -> bufB[(t+1)%3]; slot0 zeroed = h(-1).
//  - K-loop (BK=64, tile 64x128, prefetch 1 stage) unchanged from v7.
// ---------------------------------------------------------------------------

typedef __bf16 bf16x8 __attribute__((ext_vector_type(8)));
typedef float  f32x4  __attribute__((ext_vector_type(4)));

#define LDSTR 72            // LDS row stride in bf16 elems (64 data + 8 pad)
#define HSZ   (512 * 1024)  // one h buffer: 512 rows x 1024 cols (bf16)

__device__ __forceinline__ float sigm_f(float x) {
    x = fminf(30.f, fmaxf(-30.f, x));
    return 1.0f / (1.0f + __expf(-x));
}
__device__ __forceinline__ float tanh_f(float x) {
    x = fminf(30.f, fmaxf(-30.f, x));
    float e = __expf(-2.0f * x);
    return (1.0f - e) / (1.0f + e);
}

// n' = (j/16)*64 + g*16 + (j%16)  ->  original gate-major row g*1024 + j
__device__ __forceinline__ int perm_row(int np) {
    int g = (np >> 4) & 3;
    int j = ((np >> 6) << 4) | (np & 15);
    return g * 1024 + j;
}

// ---- relaxed-only flag ops (NO acquire/release -> no L2 inv/wb) ------------
__device__ __forceinline__ void spin_ge(const int* p, int target) {
    while (__hip_atomic_load(p, __ATOMIC_RELAXED, __HIP_MEMORY_SCOPE_AGENT) < target)
        __builtin_amdgcn_s_sleep(1);
}
__device__ __forceinline__ void signal_inc(int* p) {
    __hip_atomic_fetch_add(p, 1, __ATOMIC_RELAXED, __HIP_MEMORY_SCOPE_AGENT);
}
// L1-only invalidate (sc bits = 0 -> CU scope). Leaves L2/MALL intact.
__device__ __forceinline__ void inv_l1() {
    asm volatile("buffer_inv" ::: "memory");
}
// EA-point (MALL) coherent dword store: bypasses L2s -> visible chip-wide.
__device__ __forceinline__ void store_ea(unsigned* p, unsigned v) {
    __hip_atomic_store(p, v, __ATOMIC_RELAXED, __HIP_MEMORY_SCOPE_AGENT);
}

// ---------------- weight prep kernels (run every call) ----------------------

__global__ void prep_w0(const float* __restrict__ Wh0, __bf16* __restrict__ W0p) {
    int idx = blockIdx.x * 256 + threadIdx.x;
    int np = idx >> 8, k4 = (idx & 255) << 2;
    int r = perm_row(np);
    float4 v = *(const float4*)(Wh0 + r * 1024 + k4);
    __bf16* o = W0p + np * 1024 + k4;
    o[0] = (__bf16)v.x; o[1] = (__bf16)v.y; o[2] = (__bf16)v.z; o[3] = (__bf16)v.w;
}

__global__ void prep_w1(const float* __restrict__ Wi1, const float* __restrict__ Wh1,
                        __bf16* __restrict__ W1p) {
    int idx = blockIdx.x * 256 + threadIdx.x;
    int np = idx >> 9, k4 = (idx & 511) << 2;
    int r = perm_row(np);
    const float* s = (k4 < 1024) ? (Wi1 + r * 1024 + k4) : (Wh1 + r * 1024 + (k4 - 1024));
    float4 v = *(const float4*)s;
    __bf16* o = W1p + np * 2048 + k4;
    o[0] = (__bf16)v.x; o[1] = (__bf16)v.y; o[2] = (__bf16)v.z; o[3] = (__bf16)v.w;
}

__global__ void prep_wfc(const float* __restrict__ Wfc, __bf16* __restrict__ Wfcp) {
    int idx = blockIdx.x * 256 + threadIdx.x;
    int n = idx >> 8, k4 = (idx & 255) << 2;
    __bf16* o = Wfcp + n * 1024 + k4;
    if (n < 672) {
        float4 v = *(const float4*)(Wfc + n * 1024 + k4);
        o[0] = (__bf16)v.x; o[1] = (__bf16)v.y; o[2] = (__bf16)v.z; o[3] = (__bf16)v.w;
    } else {
        o[0] = (__bf16)0.f; o[1] = (__bf16)0.f; o[2] = (__bf16)0.f; o[3] = (__bf16)0.f;
    }
}

__global__ void prep_small(const float* __restrict__ Wi0, const float* __restrict__ b0,
                           const float* __restrict__ b1,
                           float* __restrict__ Wi0p, float* __restrict__ b1p) {
    int np = blockIdx.x * 256 + threadIdx.x;
    int r = perm_row(np);
    float* o = Wi0p + np * 8;
    #pragma unroll
    for (int q = 0; q < 7; ++q) o[q] = Wi0[r * 7 + q];
    o[7] = b0[r];
    b1p[np] = b1[r];
}

// ---------------- K-loop: BK=64 stages, prefetch 1 stage ahead --------------
// Tile 64x128, 256 thr = 4 waves 2x2, wave tile 32x64. A row stride 1024.
// DUAL: k<1024 from A0[m][k], k>=1024 from A1[m][k-1024]. All loads cached.

template <int KTOT, bool DUAL>
__device__ __forceinline__ void kloop(const __bf16* __restrict__ A0,
                                      const __bf16* __restrict__ A1,
                                      const __bf16* __restrict__ W,
                                      int n0, int m0, int tid,
                                      __bf16* Alds, __bf16* Blds,
                                      f32x4 (&acc)[2][4]) {
    const int a_r = tid >> 2;             // 0..63
    const int a_c = (tid & 3) << 4;       // 0,16,32,48
    const int b_r = tid >> 1;             // 0..127
    const int b_c = (tid & 1) << 5;       // 0,32
    const __bf16* wrow  = W + (size_t)(n0 + b_r) * KTOT + b_c;
    const __bf16* arow0 = A0 + (m0 + a_r) * 1024 + a_c;
    const __bf16* arow1 = DUAL ? (A1 + (m0 + a_r) * 1024 + a_c) : arow0;

    const int l  = tid & 63, w = tid >> 6;
    const int wm = w & 1,   wn = w >> 1;
    const int lj = l & 15,  lq = l >> 4;

    #pragma unroll
    for (int i = 0; i < 2; ++i)
        #pragma unroll
        for (int j = 0; j < 4; ++j)
            acc[i][j] = (f32x4){0.f, 0.f, 0.f, 0.f};

    constexpr int NIT = KTOT / 64;

    uint4 ra0, ra1, rb0, rb1, rb2, rb3;
    auto lda = [&](int k0) {
        const __bf16* p = (!DUAL || k0 < 1024) ? (arow0 + k0) : (arow1 + (k0 - 1024));
        ra0 = *(const uint4*)(p);
        ra1 = *(const uint4*)(p + 8);
    };
    auto ldb = [&](int k0) {
        const __bf16* p = wrow + k0;
        rb0 = *(const uint4*)(p);
        rb1 = *(const uint4*)(p + 8);
        rb2 = *(const uint4*)(p + 16);
        rb3 = *(const uint4*)(p + 24);
    };

    lda(0); ldb(0);

    const __bf16* Ap = Alds + (wm * 32 + lj) * LDSTR + lq * 8;
    const __bf16* Bp = Blds + (wn * 64 + lj) * LDSTR + lq * 8;

    for (int it = 0; it < NIT; ++it) {
        __syncthreads();
        *(uint4*)(Alds + a_r * LDSTR + a_c)      = ra0;
        *(uint4*)(Alds + a_r * LDSTR + a_c + 8)  = ra1;
        *(uint4*)(Blds + b_r * LDSTR + b_c)      = rb0;
        *(uint4*)(Blds + b_r * LDSTR + b_c + 8)  = rb1;
        *(uint4*)(Blds + b_r * LDSTR + b_c + 16) = rb2;
        *(uint4*)(Blds + b_r * LDSTR + b_c + 24) = rb3;
        __syncthreads();
        if (it + 1 < NIT) { int k0 = (it + 1) * 64; lda(k0); ldb(k0); }
        #pragma unroll
        for (int s = 0; s < 2; ++s) {
            bf16x8 af0 = *(const bf16x8*)(Ap + s * 32);
            bf16x8 af1 = *(const bf16x8*)(Ap + s * 32 + 16 * LDSTR);
            #pragma unroll
            for (int ni = 0; ni < 4; ++ni) {
                bf16x8 bfr = *(const bf16x8*)(Bp + s * 32 + ni * 16 * LDSTR);
                acc[0][ni] = __builtin_amdgcn_mfma_f32_16x16x32_bf16(af0, bfr, acc[0][ni], 0, 0, 0);
                acc[1][ni] = __builtin_amdgcn_mfma_f32_16x16x32_bf16(af1, bfr, acc[1][ni], 0, 0, 0);
            }
        }
    }
}

// ---------------- persistent LSTM kernel ------------------------------------
// 512 blocks, 2/CU. XCD x owns gate-column slice [512x,512x+512) of BOTH
// layers (weights L2-resident). Slot s in [0,64): s<32 -> L0 worker
// (mt=s>>2 m-tile, nb=s&3 n-subtile), s>=32 -> L1 worker likewise.
// Flags per m-tile: cA[mt] (h_a epochs, 32 producers), cB[mt] (h_b).

__global__ __launch_bounds__(256, 2)
void lstm_persist(const float* __restrict__ x,
                  const __bf16* __restrict__ W0p, const __bf16* __restrict__ W1p,
                  const __bf16* __restrict__ Wfcp,
                  const float* __restrict__ Wi0p, const float* __restrict__ b1p,
                  const float* __restrict__ bfc,
                  __bf16* __restrict__ bufA, __bf16* __restrict__ bufB,
                  char* __restrict__ flagpage, float* __restrict__ out) {
    __shared__ __attribute__((aligned(16))) __bf16 Alds[64 * LDSTR];
    __shared__ __attribute__((aligned(16))) __bf16 Blds[128 * LDSTR];
    __shared__ float Aux1[128];
    __shared__ float Xlds[64 * 9];
    __shared__ float Wxlds[128 * 9];
    __shared__ int role[2];

    const int tid = threadIdx.x;

    // ---- claim XCD-local role ----
    if (tid == 0) {
        int xcd = __builtin_amdgcn_s_getreg(63508) & 7;   // HW_REG_XCC_ID
        int* xcnt = (int*)(flagpage + 1024) + xcd;
        int slot = __hip_atomic_fetch_add(xcnt, 1, __ATOMIC_RELAXED,
                                          __HIP_MEMORY_SCOPE_AGENT);
        role[0] = xcd; role[1] = slot;
    }
    __syncthreads();
    const int xcd = role[0];
    const int s   = role[1];
    const bool isL1 = (s >= 32);
    const int sl = isL1 ? (s - 32) : s;
    const int mt = sl >> 2, nb = sl & 3;
    const int m0 = mt * 64;
    const int n0 = xcd * 512 + nb * 128;
    int* cA = (int*)(flagpage + (size_t)mt * 64);
    int* cB = (int*)(flagpage + 512 + (size_t)mt * 64);

    // one-time per-block epilogue constants
    if (isL1) {
        if (tid < 128) Aux1[tid] = b1p[n0 + tid];
    } else {
        if (tid >= 128) {
            int nl = tid - 128;
            const float* sp = Wi0p + (n0 + nl) * 8;
            float* d = Wxlds + nl * 9;
            #pragma unroll
            for (int q = 0; q < 8; ++q) d[q] = sp[q];
        }
    }

    const int l  = tid & 63, w = tid >> 6;
    const int wm = w & 1,   wn = w >> 1;
    const int lj = l & 15,  lq = l >> 4;
    const int jc = (n0 >> 2) + wn * 16 + lj;   // global h column in [0,1024)

    float cst[2][4];
    #pragma unroll
    for (int i = 0; i < 2; ++i)
        #pragma unroll
        for (int r = 0; r < 4; ++r) cst[i][r] = 0.f;

    f32x4 acc[2][4];

    if (!isL1) {
        // ============ L0 worker: gates_a(t) = h_a(t-1)@Wh0^T + x.Wi0 ========
        for (int t = 0; t < 128; ++t) {
            const __bf16* haR = bufA + (size_t)(t % 3) * HSZ;        // h_a(t-1)
            __bf16*       haW = bufA + (size_t)((t + 1) % 3) * HSZ;  // h_a(t)

            if (tid < 64) {
                const float* xr = x + (m0 + tid) * 896 + t * 7;
                float* d = Xlds + tid * 9;
                #pragma unroll
                for (int q = 0; q < 7; ++q) d[q] = xr[q];
                d[7] = 1.0f;
            }

            // RAW h_a(t-1); WAR: L1(t-3) finished reading old slot content
            if (tid == 0) { spin_ge(cA, 32 * t); spin_ge(cB, 32 * t - 64); }
            __syncthreads();
            inv_l1();
            kloop<1024, false>(haR, nullptr, W0p, n0, m0, tid, Alds, Blds, acc);

            #pragma unroll
            for (int mi = 0; mi < 2; ++mi) {
                #pragma unroll
                for (int r = 0; r < 4; ++r) {
                    int ml = wm * 32 + mi * 16 + lq * 4 + r;
                    int m  = m0 + ml;
                    float pre[4];
                    #pragma unroll
                    for (int g = 0; g < 4; ++g) pre[g] = acc[mi][g][r];
                    const float* xr = Xlds + ml * 9;
                    #pragma unroll
                    for (int g = 0; g < 4; ++g) {
                        const float* wx = Wxlds + (wn * 64 + g * 16 + lj) * 9;
                        float sv = 0.f;
                        #pragma unroll
                        for (int q = 0; q < 8; ++q) sv += xr[q] * wx[q];
                        pre[g] += sv;
                    }
                    float ig = sigm_f(pre[0]);
                    float fg = sigm_f(pre[1]);
                    float gv = tanh_f(pre[2]);
                    float og = sigm_f(pre[3]);
                    float cn = fg * cst[mi][r] + ig * gv;
                    cst[mi][r] = cn;
                    float hv = og * tanh_f(cn);
                    // pack (j, j+1) bf16 pair across lane pair, EA dword store
                    unsigned u32 = __builtin_bit_cast(unsigned, hv);
                    unsigned hu = (u32 + 0x7fffu + ((u32 >> 16) & 1u)) >> 16;
                    int pv = __shfl_xor((int)hu, 1, 64);
                    if ((lj & 1) == 0)
                        store_ea((unsigned*)(haW + (size_t)m * 1024 + jc),
                                 hu | ((unsigned)pv << 16));
                }
            }
            __syncthreads();             // vmcnt(0): EA stores performed
            if (tid == 0) signal_inc(cA);
        }

        // ---- final FC (L0 workers, nb==0, xcd<6): out = h_b(127)@Wfc^T -----
        if (nb == 0 && xcd < 6) {
            const int n0fc = xcd * 128;
            if (tid == 0) spin_ge(cB, 32 * 128);
            __syncthreads();
            inv_l1();
            if (tid < 128) {
                int n = n0fc + tid;
                Aux1[tid] = (n < 672) ? bfc[n] : 0.f;
            }
            // h_b(127) lives in bufB slot (128%3)=2
            kloop<1024, false>(bufB + (size_t)2 * HSZ, nullptr, Wfcp,
                               n0fc, m0, tid, Alds, Blds, acc);
            #pragma unroll
            for (int mi = 0; mi < 2; ++mi) {
                #pragma unroll
                for (int r = 0; r < 4; ++r) {
                    int m = m0 + wm * 32 + mi * 16 + lq * 4 + r;
                    #pragma unroll
                    for (int ni = 0; ni < 4; ++ni) {
                        int n = n0fc + wn * 64 + ni * 16 + lj;
                        if (n < 672)
                            out[m * 672 + n] = acc[mi][ni][r] + Aux1[wn * 64 + ni * 16 + lj];
                    }
                }
            }
        }
    } else {
        // ====== L1 worker: gates_b(t) = [h_a(t)|h_b(t-1)]@[Wi1|Wh1]^T + b1 ==
        for (int t = 0; t < 128; ++t) {
            const __bf16* haC = bufA + (size_t)((t + 1) % 3) * HSZ;  // h_a(t)
            const __bf16* hbR = bufB + (size_t)(t % 3) * HSZ;        // h_b(t-1)
            __bf16*       hbW = bufB + (size_t)((t + 1) % 3) * HSZ;  // h_b(t)

            if (tid == 0) { spin_ge(cA, 32 * (t + 1)); spin_ge(cB, 32 * t); }
            __syncthreads();
            inv_l1();
            kloop<2048, true>(haC, hbR, W1p, n0, m0, tid, Alds, Blds, acc);

            #pragma unroll
            for (int mi = 0; mi < 2; ++mi) {
                #pragma unroll
                for (int r = 0; r < 4; ++r) {
                    int m = m0 + wm * 32 + mi * 16 + lq * 4 + r;
                    float pre[4];
                    #pragma unroll
                    for (int g = 0; g < 4; ++g)
                        pre[g] = acc[mi][g][r] + Aux1[wn * 64 + g * 16 + lj];
                    float ig = sigm_f(pre[0]);
                    float fg = sigm_f(pre[1]);
                    float gv = tanh_f(pre[2]);
                    float og = sigm_f(pre[3]);
                    float cn = fg * cst[mi][r] + ig * gv;
                    cst[mi][r] = cn;
                    float hv = og * tanh_f(cn);
                    unsigned u32 = __builtin_bit_cast(unsigned, hv);
                    unsigned hu = (u32 + 0x7fffu + ((u32 >> 16) & 1u)) >> 16;
                    int pv = __shfl_xor((int)hu, 1, 64);
                    if ((lj & 1) == 0)
                        store_ea((unsigned*)(hbW + (size_t)m * 1024 + jc),
                                 hu | ((unsigned)pv << 16));
                }
            }
            __syncthreads();
            if (tid == 0) signal_inc(cB);
        }
    }
}

// ---------------- workspace layout (bytes) ----------------------------------
#define O_W0P   0u            // 4096*1024*2  = 8388608
#define O_W1P   8388608u      // 4096*2048*2  = 16777216
#define O_WFCP  25165824u     // 768*1024*2   = 1572864
#define O_WI0P  26738688u     // 4096*8*4     = 131072
#define O_B1P   26869760u     // 4096*4       = 16384
#define O_FLG   26886144u     // 2048: cA[8]@mt*64, cB[8]@512+mt*64, xcnt@1024
#define O_BA    26888192u     // bufA[3] = 3*1048576  (slot0 zeroed = h_a(-1))
#define O_BB    30033920u     // bufB[3] = 3*1048576  (slot0 zeroed = h_b(-1))
#define WS_NEED 33179648u

extern "C" void kernel_launch(void* const* d_in, const int* in_sizes, int n_in,
                              void* d_out, int out_size, void* d_ws, size_t ws_size,
                              hipStream_t stream) {
    const float* x   = (const float*)d_in[0];
    const float* Wi0 = (const float*)d_in[1];
    const float* Wh0 = (const float*)d_in[2];
    const float* b0  = (const float*)d_in[3];
    const float* Wi1 = (const float*)d_in[4];
    const float* Wh1 = (const float*)d_in[5];
    const float* b1  = (const float*)d_in[6];
    const float* Wfc = (const float*)d_in[7];
    const float* bfc = (const float*)d_in[8];
    float* out = (float*)d_out;
    char*  ws  = (char*)d_ws;
    if (ws_size < WS_NEED) return;

    __bf16* W0p  = (__bf16*)(ws + O_W0P);
    __bf16* W1p  = (__bf16*)(ws + O_W1P);
    __bf16* Wfcp = (__bf16*)(ws + O_WFCP);
    float*  Wi0p = (float*)(ws + O_WI0P);
    float*  b1p  = (float*)(ws + O_B1P);
    char*   flg  = (char*)(ws + O_FLG);
    __bf16* bufA = (__bf16*)(ws + O_BA);
    __bf16* bufB = (__bf16*)(ws + O_BB);

    // zero flags + bufA slot0 (contiguous), and bufB slot0
    hipMemsetAsync(ws + O_FLG, 0, 2048u + 1048576u, stream);
    hipMemsetAsync(ws + O_BB, 0, 1048576u, stream);

    prep_w0   <<<4096, 256, 0, stream>>>(Wh0, W0p);
    prep_w1   <<<8192, 256, 0, stream>>>(Wi1, Wh1, W1p);
    prep_wfc  <<<768,  256, 0, stream>>>(Wfc, Wfcp);
    prep_small<<<16,   256, 0, stream>>>(Wi0, b0, b1, Wi0p, b1p);

    lstm_persist<<<512, 256, 0, stream>>>(x, W0p, W1p, Wfcp, Wi0p, b1p, bfc,
                                          bufA, bufB, flg, out);
}

// Round 9
// 3927.051 us; speedup vs baseline: 1.3748x; 1.3748x over previous
//
#include <hip/hip_runtime.h>
#include <hip/hip_bf16.h>

// ---------------------------------------------------------------------------
// LSTM_66675072303478: 2-layer LSTM (B=512,S=128,E=7,H=1024) + FC(1024->672)
//
// v9: fused-round persistent kernel (v8's column-specialized XCD mapping).
//  - Round r computes L0(r) AND L1(r-1) in one block: both consume only
//    {h_a(r-1), h_b(r-2)} = outputs of round r-1 -> ONE chip-wide flag per
//    round (129 rounds) instead of two per step (256). h_a staged once,
//    MFMA'd against both W0p (acc0) and W1p (acc1); then h_b half (acc1).
//  - K-loop: LDS double-buffered, ONE barrier per BK=64 iter, global loads
//    issued 2 iters ahead (covers L2/MALL latency; v8 exposed it every iter).
//  - 256 blocks (1/CU): xcd (column slice, weights L2-resident) x mt(8) x
//    nb(4). Flags: cnt[mt], 32 producers each, relaxed atomics.
//  - h exchange: EA-point atomic dword stores (proven), plain cached loads
//    + 3-slot rotation + L1-only buffer_inv (v8-proven).
// ---------------------------------------------------------------------------

typedef __bf16 bf16x8 __attribute__((ext_vector_type(8)));
typedef float  f32x4  __attribute__((ext_vector_type(4)));

#define LDSTR 72            // LDS row stride in bf16 elems (64 data + 8 pad)
#define HSZ   (512 * 1024)  // one h buffer: 512 rows x 1024 cols (bf16)

__device__ __forceinline__ float sigm_f(float x) {
    x = fminf(30.f, fmaxf(-30.f, x));
    return 1.0f / (1.0f + __expf(-x));
}
__device__ __forceinline__ float tanh_f(float x) {
    x = fminf(30.f, fmaxf(-30.f, x));
    float e = __expf(-2.0f * x);
    return (1.0f - e) / (1.0f + e);
}

// n' = (j/16)*64 + g*16 + (j%16)  ->  original gate-major row g*1024 + j
__device__ __forceinline__ int perm_row(int np) {
    int g = (np >> 4) & 3;
    int j = ((np >> 6) << 4) | (np & 15);
    return g * 1024 + j;
}

// ---- relaxed-only flag ops (NO acquire/release -> no L2 inv/wb) ------------
__device__ __forceinline__ void spin_ge(const int* p, int target) {
    while (__hip_atomic_load(p, __ATOMIC_RELAXED, __HIP_MEMORY_SCOPE_AGENT) < target)
        __builtin_amdgcn_s_sleep(1);
}
__device__ __forceinline__ void signal_inc(int* p) {
    __hip_atomic_fetch_add(p, 1, __ATOMIC_RELAXED, __HIP_MEMORY_SCOPE_AGENT);
}
// L1-only invalidate (CU scope). Leaves L2/MALL intact; compiler fence.
__device__ __forceinline__ void inv_l1() {
    asm volatile("buffer_inv" ::: "memory");
}
// EA-point coherent dword store: bypasses L2s -> visible chip-wide.
__device__ __forceinline__ void store_ea(unsigned* p, unsigned v) {
    __hip_atomic_store(p, v, __ATOMIC_RELAXED, __HIP_MEMORY_SCOPE_AGENT);
}

// ---------------- weight prep kernels (run every call) ----------------------

__global__ void prep_w0(const float* __restrict__ Wh0, __bf16* __restrict__ W0p) {
    int idx = blockIdx.x * 256 + threadIdx.x;
    int np = idx >> 8, k4 = (idx & 255) << 2;
    int r = perm_row(np);
    float4 v = *(const float4*)(Wh0 + r * 1024 + k4);
    __bf16* o = W0p + np * 1024 + k4;
    o[0] = (__bf16)v.x; o[1] = (__bf16)v.y; o[2] = (__bf16)v.z; o[3] = (__bf16)v.w;
}

__global__ void prep_w1(const float* __restrict__ Wi1, const float* __restrict__ Wh1,
                        __bf16* __restrict__ W1p) {
    int idx = blockIdx.x * 256 + threadIdx.x;
    int np = idx >> 9, k4 = (idx & 511) << 2;
    int r = perm_row(np);
    const float* s = (k4 < 1024) ? (Wi1 + r * 1024 + k4) : (Wh1 + r * 1024 + (k4 - 1024));
    float4 v = *(const float4*)s;
    __bf16* o = W1p + np * 2048 + k4;
    o[0] = (__bf16)v.x; o[1] = (__bf16)v.y; o[2] = (__bf16)v.z; o[3] = (__bf16)v.w;
}

__global__ void prep_wfc(const float* __restrict__ Wfc, __bf16* __restrict__ Wfcp) {
    int idx = blockIdx.x * 256 + threadIdx.x;
    int n = idx >> 8, k4 = (idx & 255) << 2;
    __bf16* o = Wfcp + n * 1024 + k4;
    if (n < 672) {
        float4 v = *(const float4*)(Wfc + n * 1024 + k4);
        o[0] = (__bf16)v.x; o[1] = (__bf16)v.y; o[2] = (__bf16)v.z; o[3] = (__bf16)v.w;
    } else {
        o[0] = (__bf16)0.f; o[1] = (__bf16)0.f; o[2] = (__bf16)0.f; o[3] = (__bf16)0.f;
    }
}

__global__ void prep_small(const float* __restrict__ Wi0, const float* __restrict__ b0,
                           const float* __restrict__ b1,
                           float* __restrict__ Wi0p, float* __restrict__ b1p) {
    int np = blockIdx.x * 256 + threadIdx.x;
    int r = perm_row(np);
    float* o = Wi0p + np * 8;
    #pragma unroll
    for (int q = 0; q < 7; ++q) o[q] = Wi0[r * 7 + q];
    o[7] = b0[r];
    b1p[np] = b1[r];
}

// ---------------- fused pipelined K=1024 sub-loop ---------------------------
// Tile 64x128, 256 thr = 4 waves 2x2, BK=64, LDS double-buffer, 1 barrier/iter,
// loads 2 iters ahead. D0: MFMA vs W0 into acc0; D1: vs W1 into acc1.
// Caller zeros acc; this function accumulates.

template <bool D0, bool D1>
__device__ __forceinline__ void floop(const __bf16* __restrict__ arow,
                                      const __bf16* __restrict__ w0row,
                                      const __bf16* __restrict__ w1row,
                                      int tid,
                                      __bf16* AldsB, __bf16* B0ldsB, __bf16* B1ldsB,
                                      f32x4 (&acc0)[2][4], f32x4 (&acc1)[2][4]) {
    const int a_r = tid >> 2;
    const int a_c = (tid & 3) << 4;
    const int b_r = tid >> 1;
    const int b_c = (tid & 1) << 5;
    const int l  = tid & 63, w = tid >> 6;
    const int wm = w & 1,   wn = w >> 1;
    const int lj = l & 15,  lq = l >> 4;

    uint4 ra0, ra1, rb00, rb01, rb02, rb03, rb10, rb11, rb12, rb13;
    auto ld = [&](int k0) {
        const __bf16* pa = arow + k0;
        ra0 = *(const uint4*)(pa);
        ra1 = *(const uint4*)(pa + 8);
        if (D0) {
            const __bf16* p = w0row + k0;
            rb00 = *(const uint4*)(p);      rb01 = *(const uint4*)(p + 8);
            rb02 = *(const uint4*)(p + 16); rb03 = *(const uint4*)(p + 24);
        }
        if (D1) {
            const __bf16* p = w1row + k0;
            rb10 = *(const uint4*)(p);      rb11 = *(const uint4*)(p + 8);
            rb12 = *(const uint4*)(p + 16); rb13 = *(const uint4*)(p + 24);
        }
    };
    auto wr = [&](int buf) {
        __bf16* Al = AldsB + buf * (64 * LDSTR);
        *(uint4*)(Al + a_r * LDSTR + a_c)     = ra0;
        *(uint4*)(Al + a_r * LDSTR + a_c + 8) = ra1;
        if (D0) {
            __bf16* Bl = B0ldsB + buf * (128 * LDSTR);
            *(uint4*)(Bl + b_r * LDSTR + b_c)      = rb00;
            *(uint4*)(Bl + b_r * LDSTR + b_c + 8)  = rb01;
            *(uint4*)(Bl + b_r * LDSTR + b_c + 16) = rb02;
            *(uint4*)(Bl + b_r * LDSTR + b_c + 24) = rb03;
        }
        if (D1) {
            __bf16* Bl = B1ldsB + buf * (128 * LDSTR);
            *(uint4*)(Bl + b_r * LDSTR + b_c)      = rb10;
            *(uint4*)(Bl + b_r * LDSTR + b_c + 8)  = rb11;
            *(uint4*)(Bl + b_r * LDSTR + b_c + 16) = rb12;
            *(uint4*)(Bl + b_r * LDSTR + b_c + 24) = rb13;
        }
    };

    // prologue: stage 0 into buf0, stage 1 in regs
    ld(0);
    wr(0);
    ld(64);
    __syncthreads();

    const __bf16* Ap  = AldsB  + (wm * 32 + lj) * LDSTR + lq * 8;
    const __bf16* B0p = B0ldsB + (wn * 64 + lj) * LDSTR + lq * 8;
    const __bf16* B1p = B1ldsB + (wn * 64 + lj) * LDSTR + lq * 8;

    for (int it = 0; it < 16; ++it) {
        const int bo = it & 1;
        const __bf16* Ab  = Ap  + bo * (64 * LDSTR);
        const __bf16* B0b = B0p + bo * (128 * LDSTR);
        const __bf16* B1b = B1p + bo * (128 * LDSTR);
        #pragma unroll
        for (int s = 0; s < 2; ++s) {
            bf16x8 af0 = *(const bf16x8*)(Ab + s * 32);
            bf16x8 af1 = *(const bf16x8*)(Ab + s * 32 + 16 * LDSTR);
            #pragma unroll
            for (int ni = 0; ni < 4; ++ni) {
                if (D0) {
                    bf16x8 b0 = *(const bf16x8*)(B0b + s * 32 + ni * 16 * LDSTR);
                    acc0[0][ni] = __builtin_amdgcn_mfma_f32_16x16x32_bf16(af0, b0, acc0[0][ni], 0, 0, 0);
                    acc0[1][ni] = __builtin_amdgcn_mfma_f32_16x16x32_bf16(af1, b0, acc0[1][ni], 0, 0, 0);
                }
                if (D1) {
                    bf16x8 b1 = *(const bf16x8*)(B1b + s * 32 + ni * 16 * LDSTR);
                    acc1[0][ni] = __builtin_amdgcn_mfma_f32_16x16x32_bf16(af0, b1, acc1[0][ni], 0, 0, 0);
                    acc1[1][ni] = __builtin_amdgcn_mfma_f32_16x16x32_bf16(af1, b1, acc1[1][ni], 0, 0, 0);
                }
            }
        }
        if (it + 1 < 16) wr((it + 1) & 1);       // data loaded 1 iter ago
        if (it + 2 < 16) ld((it + 2) * 64);      // 2-iter prefetch distance
        __syncthreads();
    }
}

// ---------------- persistent fused LSTM kernel ------------------------------
// 256 blocks, 1/CU. xcd owns gate-col slice [512x,512x+512) of both layers;
// slot -> mt (0..7, 64-row stripe) x nb (0..3, 128-gate subtile).
// Round r (0..128): L0(r) [r<128] + L1(r-1) [r>0]; one flag inc per round.

__global__ __launch_bounds__(256)
void lstm_persist(const float* __restrict__ x,
                  const __bf16* __restrict__ W0p, const __bf16* __restrict__ W1p,
                  const __bf16* __restrict__ Wfcp,
                  const float* __restrict__ Wi0p, const float* __restrict__ b1p,
                  const float* __restrict__ bfc,
                  __bf16* __restrict__ bufA, __bf16* __restrict__ bufB,
                  char* __restrict__ flagpage, float* __restrict__ out) {
    __shared__ __attribute__((aligned(16))) __bf16 Alds[2 * 64 * LDSTR];
    __shared__ __attribute__((aligned(16))) __bf16 B0lds[2 * 128 * LDSTR];
    __shared__ __attribute__((aligned(16))) __bf16 B1lds[2 * 128 * LDSTR];
    __shared__ float Aux1[128];
    __shared__ float Xlds[64 * 9];
    __shared__ float Wxlds[128 * 9];
    __shared__ int role[2];

    const int tid = threadIdx.x;

    // ---- claim XCD-local role ----
    if (tid == 0) {
        int xcd = __builtin_amdgcn_s_getreg(63508) & 7;   // HW_REG_XCC_ID
        int* xcnt = (int*)(flagpage + 1024) + xcd;
        int slot = __hip_atomic_fetch_add(xcnt, 1, __ATOMIC_RELAXED,
                                          __HIP_MEMORY_SCOPE_AGENT);
        role[0] = xcd; role[1] = slot;
    }
    __syncthreads();
    const int xcd = role[0];
    const int sl  = role[1];          // 0..31
    const int mt = sl >> 2, nb = sl & 3;
    const int m0 = mt * 64;
    const int n0 = xcd * 512 + nb * 128;
    int* cnt = (int*)(flagpage + (size_t)mt * 64);

    // one-time epilogue constants
    if (tid < 128) {
        Aux1[tid] = b1p[n0 + tid];
    } else {
        int nl = tid - 128;
        const float* sp = Wi0p + (n0 + nl) * 8;
        float* d = Wxlds + nl * 9;
        #pragma unroll
        for (int q = 0; q < 8; ++q) d[q] = sp[q];
    }

    const int a_r = tid >> 2;
    const int a_c = (tid & 3) << 4;
    const int b_r = tid >> 1;
    const int b_c = (tid & 1) << 5;
    const int l  = tid & 63, w = tid >> 6;
    const int wm = w & 1,   wn = w >> 1;
    const int lj = l & 15,  lq = l >> 4;
    const int jc = (n0 >> 2) + wn * 16 + lj;   // h column in [0,1024)

    const __bf16* w0row = W0p + (size_t)(n0 + b_r) * 1024 + b_c;
    const __bf16* w1row = W1p + (size_t)(n0 + b_r) * 2048 + b_c;

    float c0[2][4], c1[2][4];
    #pragma unroll
    for (int i = 0; i < 2; ++i)
        #pragma unroll
        for (int r = 0; r < 4; ++r) { c0[i][r] = 0.f; c1[i][r] = 0.f; }

    f32x4 acc0[2][4], acc1[2][4];

    for (int r = 0; r <= 128; ++r) {
        const bool do0 = (r < 128), do1 = (r > 0);
        const __bf16* haPrev = bufA + (size_t)(r % 3) * HSZ;        // h_a(r-1)
        __bf16*       haOut  = bufA + (size_t)((r + 1) % 3) * HSZ;  // h_a(r)
        const __bf16* hbPrev = bufB + (size_t)((r + 2) % 3) * HSZ;  // h_b(r-2)
        __bf16*       hbOut  = bufB + (size_t)(r % 3) * HSZ;        // h_b(r-1)

        if (tid == 0) spin_ge(cnt, 32 * r);
        __syncthreads();
        inv_l1();

        // stage x_r (read-only input; Xlds(r-1) reads ended before round barrier)
        if (do0 && tid < 64) {
            const float* xr = x + (m0 + tid) * 896 + r * 7;
            float* d = Xlds + tid * 9;
            #pragma unroll
            for (int q = 0; q < 7; ++q) d[q] = xr[q];
            d[7] = 1.0f;
        }

        #pragma unroll
        for (int i = 0; i < 2; ++i)
            #pragma unroll
            for (int j = 0; j < 4; ++j) {
                acc0[i][j] = (f32x4){0.f, 0.f, 0.f, 0.f};
                acc1[i][j] = (f32x4){0.f, 0.f, 0.f, 0.f};
            }

        const __bf16* arow = haPrev + (m0 + a_r) * 1024 + a_c;
        if (do0 && do1)
            floop<true, true >(arow, w0row, w1row, tid, Alds, B0lds, B1lds, acc0, acc1);
        else if (do0)
            floop<true, false>(arow, w0row, w1row, tid, Alds, B0lds, B1lds, acc0, acc1);
        else
            floop<false, true>(arow, w0row, w1row, tid, Alds, B0lds, B1lds, acc0, acc1);

        if (do1) {   // h_b(r-2) half of layer-1 GEMM (k in [1024,2048))
            const __bf16* arow2 = hbPrev + (m0 + a_r) * 1024 + a_c;
            floop<false, true>(arow2, w0row, w1row + 1024, tid, Alds, B0lds, B1lds, acc0, acc1);
        }

        if (do0) {   // L0 epilogue: cell update + EA store h_a(r)
            #pragma unroll
            for (int mi = 0; mi < 2; ++mi) {
                #pragma unroll
                for (int rr = 0; rr < 4; ++rr) {
                    int ml = wm * 32 + mi * 16 + lq * 4 + rr;
                    int m  = m0 + ml;
                    float pre[4];
                    #pragma unroll
                    for (int g = 0; g < 4; ++g) pre[g] = acc0[mi][g][rr];
                    const float* xr = Xlds + ml * 9;
                    #pragma unroll
                    for (int g = 0; g < 4; ++g) {
                        const float* wx = Wxlds + (wn * 64 + g * 16 + lj) * 9;
                        float sv = 0.f;
                        #pragma unroll
                        for (int q = 0; q < 8; ++q) sv += xr[q] * wx[q];
                        pre[g] += sv;
                    }
                    float ig = sigm_f(pre[0]);
                    float fg = sigm_f(pre[1]);
                    float gv = tanh_f(pre[2]);
                    float og = sigm_f(pre[3]);
                    float cn = fg * c0[mi][rr] + ig * gv;
                    c0[mi][rr] = cn;
                    float hv = og * tanh_f(cn);
                    unsigned u32 = __builtin_bit_cast(unsigned, hv);
                    unsigned hu = (u32 + 0x7fffu + ((u32 >> 16) & 1u)) >> 16;
                    int pv = __shfl_xor((int)hu, 1, 64);
                    if ((lj & 1) == 0)
                        store_ea((unsigned*)(haOut + (size_t)m * 1024 + jc),
                                 hu | ((unsigned)pv << 16));
                }
            }
        }
        if (do1) {   // L1 epilogue: cell update + EA store h_b(r-1)
            #pragma unroll
            for (int mi = 0; mi < 2; ++mi) {
                #pragma unroll
                for (int rr = 0; rr < 4; ++rr) {
                    int m = m0 + wm * 32 + mi * 16 + lq * 4 + rr;
                    float pre[4];
                    #pragma unroll
                    for (int g = 0; g < 4; ++g)
                        pre[g] = acc1[mi][g][rr] + Aux1[wn * 64 + g * 16 + lj];
                    float ig = sigm_f(pre[0]);
                    float fg = sigm_f(pre[1]);
                    float gv = tanh_f(pre[2]);
                    float og = sigm_f(pre[3]);
                    float cn = fg * c1[mi][rr] + ig * gv;
                    c1[mi][rr] = cn;
                    float hv = og * tanh_f(cn);
                    unsigned u32 = __builtin_bit_cast(unsigned, hv);
                    unsigned hu = (u32 + 0x7fffu + ((u32 >> 16) & 1u)) >> 16;
                    int pv = __shfl_xor((int)hu, 1, 64);
                    if ((lj & 1) == 0)
                        store_ea((unsigned*)(hbOut + (size_t)m * 1024 + jc),
                                 hu | ((unsigned)pv << 16));
                }
            }
        }
        __syncthreads();                 // vmcnt(0): EA stores performed
        if (tid == 0) signal_inc(cnt);
    }

    // ---- final FC: pred = h_b(127) @ Wfc^T + bfc  (nb==0, xcd<6) -----------
    if (nb == 0 && xcd < 6) {
        const int n0fc = xcd * 128;
        if (tid == 0) spin_ge(cnt, 32 * 129);
        __syncthreads();
        inv_l1();
        if (tid < 128) {
            int n = n0fc + tid;
            Aux1[tid] = (n < 672) ? bfc[n] : 0.f;
        }
        #pragma unroll
        for (int i = 0; i < 2; ++i)
            #pragma unroll
            for (int j = 0; j < 4; ++j)
                acc0[i][j] = (f32x4){0.f, 0.f, 0.f, 0.f};
        // h_b(127) written in round 128 into bufB slot 128%3 = 2
        const __bf16* arowf = bufB + (size_t)2 * HSZ + (m0 + a_r) * 1024 + a_c;
        const __bf16* wfrow = Wfcp + (size_t)(n0fc + b_r) * 1024 + b_c;
        floop<true, false>(arowf, wfrow, wfrow, tid, Alds, B0lds, B1lds, acc0, acc1);
        #pragma unroll
        for (int mi = 0; mi < 2; ++mi) {
            #pragma unroll
            for (int rr = 0; rr < 4; ++rr) {
                int m = m0 + wm * 32 + mi * 16 + lq * 4 + rr;
                #pragma unroll
                for (int ni = 0; ni < 4; ++ni) {
                    int n = n0fc + wn * 64 + ni * 16 + lj;
                    if (n < 672)
                        out[m * 672 + n] = acc0[mi][ni][rr] + Aux1[wn * 64 + ni * 16 + lj];
                }
            }
        }
    }
}

// ---------------- workspace layout (bytes) ----------------------------------
#define O_W0P   0u            // 4096*1024*2  = 8388608
#define O_W1P   8388608u      // 4096*2048*2  = 16777216
#define O_WFCP  25165824u     // 768*1024*2   = 1572864
#define O_WI0P  26738688u     // 4096*8*4     = 131072
#define O_B1P   26869760u     // 4096*4       = 16384
#define O_FLG   26886144u     // 2048: cnt[8]@mt*64, xcnt@1024
#define O_BA    26888192u     // bufA[3] = 3*1048576  (slot0 zeroed = h_a(-1))
#define O_BB    30033920u     // bufB[3] = 3*1048576  (slot0 zeroed = h_b(-1))
#define WS_NEED 33179648u

extern "C" void kernel_launch(void* const* d_in, const int* in_sizes, int n_in,
                              void* d_out, int out_size, void* d_ws, size_t ws_size,
                              hipStream_t stream) {
    const float* x   = (const float*)d_in[0];
    const float* Wi0 = (const float*)d_in[1];
    const float* Wh0 = (const float*)d_in[2];
    const float* b0  = (const float*)d_in[3];
    const float* Wi1 = (const float*)d_in[4];
    const float* Wh1 = (const float*)d_in[5];
    const float* b1  = (const float*)d_in[6];
    const float* Wfc = (const float*)d_in[7];
    const float* bfc = (const float*)d_in[8];
    float* out = (float*)d_out;
    char*  ws  = (char*)d_ws;
    if (ws_size < WS_NEED) return;

    __bf16* W0p  = (__bf16*)(ws + O_W0P);
    __bf16* W1p  = (__bf16*)(ws + O_W1P);
    __bf16* Wfcp = (__bf16*)(ws + O_WFCP);
    float*  Wi0p = (float*)(ws + O_WI0P);
    float*  b1p  = (float*)(ws + O_B1P);
    char*   flg  = (char*)(ws + O_FLG);
    __bf16* bufA = (__bf16*)(ws + O_BA);
    __bf16* bufB = (__bf16*)(ws + O_BB);

    // zero flags + bufA slot0 (contiguous), and bufB slot0
    hipMemsetAsync(ws + O_FLG, 0, 2048u + 1048576u, stream);
    hipMemsetAsync(ws + O_BB, 0, 1048576u, stream);

    prep_w0   <<<4096, 256, 0, stream>>>(Wh0, W0p);
    prep_w1   <<<8192, 256, 0, stream>>>(Wi1, Wh1, W1p);
    prep_wfc  <<<768,  256, 0, stream>>>(Wfc, Wfcp);
    prep_small<<<16,   256, 0, stream>>>(Wi0, b0, b1, Wi0p, b1p);

    lstm_persist<<<256, 256, 0, stream>>>(x, W0p, W1p, Wfcp, Wi0p, b1p, bfc,
                                          bufA, bufB, flg, out);
}